// Round 5
// baseline (248.604 us; speedup 1.0000x reference)
//
#include <hip/hip_runtime.h>
#include <cstddef>

// Shapes: B=8, CIN=128, N=2048, K=16, G=4, COUT=256, L=192, CL=48, NL=64, CNL=16
constexpr int NN = 2048;
constexpr int GG = 4;

// ---------------------------------------------------------------------------
// prep_q: Qbuf[g][c2][row] f32 (row<64: M_g[row][c2] = sum_o Wk[o][row]Wq[o][c2];
// row>=64: W2q_g[row-64][c2] = sum_o pe_w2[row-64][o]Wq[o][c2]), o in group g.
// ---------------------------------------------------------------------------
__global__ __launch_bounds__(256) void prep_q(const float* __restrict__ Wq,
                                              const float* __restrict__ Wk,
                                              const float* __restrict__ pe_w2,
                                              float* __restrict__ Qbuf) {
    const int g = blockIdx.x >> 6, c2 = blockIdx.x & 63;
    const int row = threadIdx.x;
    float acc = 0.f;
    if (row < 64) {
        for (int j = 0; j < 48; ++j) {
            const int o = g * 48 + j;
            acc = fmaf(Wk[o * 64 + row], Wq[o * 64 + c2], acc);
        }
    } else {
        const int d = row - 64;
        for (int j = 0; j < 48; ++j) {
            const int o = g * 48 + j;
            acc = fmaf(pe_w2[(size_t)d * 192 + o], Wq[o * 64 + c2], acc);
        }
    }
    Qbuf[((size_t)(g * 64 + c2) << 8) + row] = acc;
}

// ---------------------------------------------------------------------------
// local_v5: NTILE=4, ~28KB LDS -> 5 blocks/CU. f32 logits (top-k safe).
// Block = (b, 4 n). x read straight from global (L3-resident) twice.
// ---------------------------------------------------------------------------
__global__ __launch_bounds__(256, 4) void local_v5(
    const float* __restrict__ x, const float* __restrict__ abs_x,
    const float* __restrict__ points, const float* __restrict__ Wv,
    const float* __restrict__ pe_w1, const float* __restrict__ pe_b1,
    const int* __restrict__ idx, const float* __restrict__ Qbuf,
    float* __restrict__ out, float* __restrict__ cent)
{
    const int bn = blockIdx.x;
    const int b  = bn >> 9;
    const int n0 = (bn & 511) << 2;
    const int tid = threadIdx.x;

    __shared__ int   sidx[64];
    __shared__ float sa2[64][4];
    __shared__ float spts[3][4][16];
    __shared__ float sq[4][4][65];                    // q~ per (g,nl,c2)
    __shared__ __align__(16) float s_union[3104];     // sw then sxw
    __shared__ float spartA[64][17];                  // logitA partials (ch*4+g)
    __shared__ float spartB[64][17];                  // logitB partials (dh*4+g)
    __shared__ float satt[4][64];

    float* sw  = s_union;                             // sw[(g*4+nl)*193 + d]
    float* sxw = s_union;                             // sxw[(g*128+c)*4 + nl]

    // ---- stage0: idx, a2 ----
    if (tid < 64) sidx[tid] = idx[((size_t)b * NN + n0) * 16 + tid];
    if (tid < 256) {
        int c = tid >> 2, nl = tid & 3;
        sa2[c][nl] = abs_x[((size_t)b * 64 + c) * NN + n0 + nl];
    }
    __syncthreads();

    // ---- spts gather + Q-stage: [q~; w~](row=tid) = Qbuf_g @ a2 ----
    if (tid < 192) {
        int c = tid >> 6, r = tid & 63;
        spts[c][r >> 4][r & 15] = points[((size_t)b * 3 + c) * NN + sidx[r]];
    }
    #pragma unroll
    for (int g = 0; g < 4; ++g) {
        const float* qb = Qbuf + ((size_t)g << 14) + tid;   // (g*64+c2)*256 + row
        float a0 = 0.f, a1 = 0.f, a2v = 0.f, a3 = 0.f;
        for (int c2 = 0; c2 < 64; ++c2) {
            const float qv = qb[c2 << 8];
            const float4 av = *(const float4*)&sa2[c2][0];
            a0 = fmaf(qv, av.x, a0); a1 = fmaf(qv, av.y, a1);
            a2v = fmaf(qv, av.z, a2v); a3 = fmaf(qv, av.w, a3);
        }
        if (tid < 64) {
            sq[g][0][tid] = a0; sq[g][1][tid] = a1;
            sq[g][2][tid] = a2v; sq[g][3][tid] = a3;
        } else {
            const int d = tid - 64;
            sw[((g << 2) + 0) * 193 + d] = a0;
            sw[((g << 2) + 1) * 193 + d] = a1;
            sw[((g << 2) + 2) * 193 + d] = a2v;
            sw[((g << 2) + 3) * 193 + d] = a3;
        }
    }
    __syncthreads();

    // ---- logitA partials: spartA[col][ch*4+g], c-range 16 per ch ----
    {
        const int col = tid & 63, ch = tid >> 6;      // c in [ch*16, ch*16+16)
        const int nl = col >> 4, kk = col & 15;
        const float* xp = x + (((size_t)(b * 128 + ch * 16) * NN) + n0 + nl) * 16 + kk;
        const float* q0 = &sq[0][nl][ch * 16];
        const float* q1 = &sq[1][nl][ch * 16];
        const float* q2 = &sq[2][nl][ch * 16];
        const float* q3 = &sq[3][nl][ch * 16];
        float a0 = 0.f, a1 = 0.f, a2v = 0.f, a3 = 0.f;
        #pragma unroll 4
        for (int i = 0; i < 16; ++i) {
            const float xs = xp[0] + xp[(size_t)64 * NN * 16];
            xp += NN * 16;
            a0 = fmaf(q0[i], xs, a0);
            a1 = fmaf(q1[i], xs, a1);
            a2v = fmaf(q2[i], xs, a2v);
            a3 = fmaf(q3[i], xs, a3);
        }
        spartA[col][ch * 4 + 0] = a0; spartA[col][ch * 4 + 1] = a1;
        spartA[col][ch * 4 + 2] = a2v; spartA[col][ch * 4 + 3] = a3;
    }
    // ---- logitB partials: spartB[col][dh*4+g], d-range 48 per dh ----
    {
        const int col = tid & 63, dh = tid >> 6;      // d in [dh*48, dh*48+48)
        const int nl = col >> 4, kk = col & 15;
        const float r0 = spts[0][nl][kk] - spts[0][nl][0];
        const float r1 = spts[1][nl][kk] - spts[1][nl][0];
        const float r2 = spts[2][nl][kk] - spts[2][nl][0];
        float p0 = 0.f, p1 = 0.f, p2 = 0.f, p3 = 0.f;
        const int d0 = dh * 48;
        const float* w0 = &sw[((0 << 2) + nl) * 193];
        const float* w1 = &sw[((1 << 2) + nl) * 193];
        const float* w2 = &sw[((2 << 2) + nl) * 193];
        const float* w3 = &sw[((3 << 2) + nl) * 193];
        for (int d = d0; d < d0 + 48; ++d) {
            float h = fmaf(r0, pe_w1[d], fmaf(r1, pe_w1[192 + d], fmaf(r2, pe_w1[384 + d], pe_b1[d])));
            h = fmaxf(h, 0.f);
            p0 = fmaf(h, w0[d], p0);
            p1 = fmaf(h, w1[d], p1);
            p2 = fmaf(h, w2[d], p2);
            p3 = fmaf(h, w3[d], p3);
        }
        spartB[col][dh * 4 + 0] = p0; spartB[col][dh * 4 + 1] = p1;
        spartB[col][dh * 4 + 2] = p2; spartB[col][dh * 4 + 3] = p3;
    }
    __syncthreads();

    // ---- prefetch x for the xw phase (independent of softmax) ----
    float xv[2][16];
    #pragma unroll
    for (int t = 0; t < 2; ++t) {
        const int i2 = t * 256 + tid;
        const int c = i2 >> 2, nl = i2 & 3;
        const float* xp = x + (((size_t)(b * 128 + c) * NN) + n0 + nl) * 16;
        *(float4*)&xv[t][0]  = *(const float4*)(xp);
        *(float4*)&xv[t][4]  = *(const float4*)(xp + 4);
        *(float4*)&xv[t][8]  = *(const float4*)(xp + 8);
        *(float4*)&xv[t][12] = *(const float4*)(xp + 12);
    }

    // ---- softmax over kk per (g,nl); scatter att into cent ----
    if (tid < 16) {
        const int g = tid >> 2, nl = tid & 3;
        float lg[16], m = -1e30f;
        #pragma unroll
        for (int kk = 0; kk < 16; ++kk) {
            const int col = nl * 16 + kk;
            lg[kk] = (spartA[col][g] + spartA[col][4 + g] + spartA[col][8 + g] + spartA[col][12 + g])
                   + (spartB[col][g] + spartB[col][4 + g] + spartB[col][8 + g] + spartB[col][12 + g]);
            m = fmaxf(m, lg[kk]);
        }
        float s = 0.f;
        #pragma unroll
        for (int kk = 0; kk < 16; ++kk) { lg[kk] = __expf(lg[kk] - m); s += lg[kk]; }
        const float inv = 1.f / s;
        #pragma unroll
        for (int kk = 0; kk < 16; ++kk) {
            const float a = lg[kk] * inv;
            satt[g][nl * 16 + kk] = a;
            atomicAdd(&cent[((size_t)(b * GG + g) << 11) + sidx[nl * 16 + kk]], a);
        }
    }
    __syncthreads();

    // ---- xw[g][c][nl] = sum_kk x[c][nl*16+kk]*att[g][...] ----
    #pragma unroll
    for (int t = 0; t < 2; ++t) {
        const int i2 = t * 256 + tid;
        const int c = i2 >> 2, nl = i2 & 3;
        #pragma unroll
        for (int g = 0; g < 4; ++g) {
            float v = 0.f;
            #pragma unroll
            for (int kk = 0; kk < 16; ++kk) v = fmaf(xv[t][kk], satt[g][nl * 16 + kk], v);
            sxw[(((g << 7) + c) << 2) + nl] = v;
        }
    }
    __syncthreads();

    // ---- out[o][n] = Wv[o,:] . xw[g(o)][:,n] ----
    #pragma unroll
    for (int rep = 0; rep < 3; ++rep) {
        const int i = rep * 256 + tid;
        const int o = i >> 2, nl = i & 3;
        const int g = o / 48;
        const float* wv = Wv + (size_t)o * 128;
        const float* xwp = &sxw[((size_t)(g << 7) << 2) + nl];
        float a = 0.f;
        for (int c = 0; c < 128; c += 4) {
            const float4 w4 = *(const float4*)(wv + c);
            a = fmaf(w4.x, xwp[(c + 0) << 2], a);
            a = fmaf(w4.y, xwp[(c + 1) << 2], a);
            a = fmaf(w4.z, xwp[(c + 2) << 2], a);
            a = fmaf(w4.w, xwp[(c + 3) << 2], a);
        }
        out[(((size_t)b << 8) + o) * NN + n0 + nl] = a;
    }
}

// ---------------------------------------------------------------------------
// Kernel C: per (b,g): top-16 of cent row, then nonlocal prep (unchanged).
// ---------------------------------------------------------------------------
__global__ __launch_bounds__(256) void topk_prep_kernel(
    const float* __restrict__ abs_x, const float* __restrict__ points,
    const float* __restrict__ Wnk, const float* __restrict__ Wnv2,
    const float* __restrict__ npe_w1, const float* __restrict__ npe_b1,
    const float* __restrict__ npe_w2, const float* __restrict__ npe_b2,
    const float* __restrict__ cent,
    float* __restrict__ nkpe, float* __restrict__ nv2j, float* __restrict__ tanhv)
{
    const int bg  = blockIdx.x;
    const int b   = bg >> 2, g = bg & 3;
    const int tid = threadIdx.x;
    __shared__ float sc[2048];
    __shared__ float rv[4];  __shared__ int ri[4];
    __shared__ float svals[16]; __shared__ int sinds[16];
    __shared__ float srel[3][16];
    __shared__ float sh2[16][16];

    for (int i = tid; i < 2048; i += 256) sc[i] = cent[((size_t)bg << 11) + i];
    __syncthreads();
    for (int t = 0; t < 16; ++t) {
        float bv = -1e30f; int bi = 1 << 30;
        for (int i = tid; i < 2048; i += 256) {
            float v = sc[i];
            if (v > bv) { bv = v; bi = i; }
        }
        #pragma unroll
        for (int off = 1; off < 64; off <<= 1) {
            float ov = __shfl_xor(bv, off, 64);
            int   oi = __shfl_xor(bi, off, 64);
            if (ov > bv || (ov == bv && oi < bi)) { bv = ov; bi = oi; }
        }
        if ((tid & 63) == 0) { rv[tid >> 6] = bv; ri[tid >> 6] = bi; }
        __syncthreads();
        if (tid == 0) {
            for (int w = 1; w < 4; ++w)
                if (rv[w] > bv || (rv[w] == bv && ri[w] < bi)) { bv = rv[w]; bi = ri[w]; }
            svals[t] = bv; sinds[t] = bi;
            sc[bi] = -1e30f;
        }
        __syncthreads();
    }

    if (tid < 48) {
        int c = tid >> 4, j = tid & 15;
        srel[c][j] = points[((size_t)b * 3 + c) * NN + sinds[j]]
                   - points[((size_t)b * 3 + c) * NN + sinds[0]];
    }
    __syncthreads();
    {
        int j = tid >> 4, d = tid & 15;
        float a = npe_b1[g * 16 + d];
        #pragma unroll
        for (int c = 0; c < 3; ++c) a = fmaf(srel[c][j], npe_w1[((g * 3 + c) << 4) + d], a);
        sh2[j][d] = fmaxf(a, 0.f);
    }
    __syncthreads();
    {
        int c = tid >> 4, j = tid & 15;
        float a = npe_b2[g * 16 + c];
        #pragma unroll
        for (int d = 0; d < 16; ++d) a = fmaf(sh2[j][d], npe_w2[((g * 16 + d) << 4) + c], a);
        float nk = 0.f, nv = 0.f;
        const int col = sinds[j];
        const float* a2  = abs_x + (size_t)b * 64 * NN + col;
        const float* wkr = Wnk  + ((size_t)(g * 16 + c) << 6);
        const float* wvr = Wnv2 + ((size_t)(g * 16 + c) << 6);
        for (int ci = 0; ci < 64; ++ci) {
            float av = a2[(size_t)ci * NN];
            nk = fmaf(wkr[ci], av, nk);
            nv = fmaf(wvr[ci], av, nv);
        }
        nkpe[((size_t)bg << 8) + (c << 4) + j] = nk + a;
        nv2j[((size_t)bg << 8) + (c << 4) + j] = nv;
    }
    if (tid < 16) tanhv[(bg << 4) + tid] = tanhf(svals[tid]);
}

// ---------------------------------------------------------------------------
// Kernel D: nonlocal branch (unchanged).
// ---------------------------------------------------------------------------
__global__ __launch_bounds__(256) void nonlocal_kernel(
    const float* __restrict__ abs_x,
    const float* __restrict__ Wnq, const float* __restrict__ Wnv1, const float* __restrict__ Wnv2,
    const float* __restrict__ nkpe, const float* __restrict__ nv2j, const float* __restrict__ tanhv,
    float* __restrict__ out)
{
    const int blk = blockIdx.x;
    const int b   = blk >> 5;
    const int n0  = (blk & 31) << 6;
    const int tid = threadIdx.x;
    const int nl  = tid & 63;
    const int g   = tid >> 6;

    __shared__ float sa2[64][64];
    __shared__ float snkpe[4][16][16];
    __shared__ float snv2j[4][16][16];
    __shared__ float stanh[4][16];

    for (int i = tid; i < 64 * 64; i += 256) {
        int ci = i >> 6, c2 = i & 63;
        sa2[ci][c2] = abs_x[((size_t)b * 64 + ci) * NN + n0 + c2];
    }
    for (int i = tid; i < 1024; i += 256) {
        ((float*)snkpe)[i] = nkpe[((size_t)b << 10) + i];
        ((float*)snv2j)[i] = nv2j[((size_t)b << 10) + i];
    }
    if (tid < 64) ((float*)stanh)[tid] = tanhv[(b << 6) + tid];
    __syncthreads();

    float nq[16], nv1[16], nv2[16];
    #pragma unroll
    for (int c = 0; c < 16; ++c) { nq[c] = 0.f; nv1[c] = 0.f; nv2[c] = 0.f; }
    const float* wq  = Wnq  + (size_t)(g << 4) * 64;
    const float* wv1 = Wnv1 + (size_t)(g << 4) * 64;
    const float* wv2 = Wnv2 + (size_t)(g << 4) * 64;
    for (int ci = 0; ci < 64; ++ci) {
        const float a = sa2[ci][nl];
        #pragma unroll
        for (int c = 0; c < 16; ++c) {
            nq[c]  = fmaf(wq [(c << 6) + ci], a, nq[c]);
            nv1[c] = fmaf(wv1[(c << 6) + ci], a, nv1[c]);
            nv2[c] = fmaf(wv2[(c << 6) + ci], a, nv2[c]);
        }
    }

    float lg[16];
    #pragma unroll
    for (int j = 0; j < 16; ++j) {
        float a = 0.f;
        #pragma unroll
        for (int c = 0; c < 16; ++c) a = fmaf(nq[c], snkpe[g][c][j], a);
        lg[j] = a;
    }
    float m = lg[0];
    #pragma unroll
    for (int j = 1; j < 16; ++j) m = fmaxf(m, lg[j]);
    float s = 0.f;
    float w[16];
    #pragma unroll
    for (int j = 0; j < 16; ++j) { w[j] = __expf(lg[j] - m); s += w[j]; }
    const float inv = 1.f / s;
    float ws = 0.f;
    #pragma unroll
    for (int j = 0; j < 16; ++j) { w[j] = w[j] * inv * stanh[g][j]; ws += w[j]; }
    #pragma unroll
    for (int c = 0; c < 16; ++c) {
        float v = (nv1[c] - nv2[c]) * ws;
        #pragma unroll
        for (int j = 0; j < 16; ++j) v = fmaf(w[j], snv2j[g][c][j], v);
        out[(((size_t)b << 8) + 192 + (g << 4) + c) * NN + n0 + nl] = v;
    }
}

// ---------------------------------------------------------------------------
extern "C" void kernel_launch(void* const* d_in, const int* in_sizes, int n_in,
                              void* d_out, int out_size, void* d_ws, size_t ws_size,
                              hipStream_t stream)
{
    (void)in_sizes; (void)n_in; (void)out_size; (void)ws_size;
    const float* x      = (const float*)d_in[0];
    const float* abs_x  = (const float*)d_in[1];
    const float* points = (const float*)d_in[2];
    const float* Wq     = (const float*)d_in[3];
    const float* Wk     = (const float*)d_in[4];
    const float* Wv     = (const float*)d_in[5];
    const float* Wnq    = (const float*)d_in[6];
    const float* Wnk    = (const float*)d_in[7];
    const float* Wnv1   = (const float*)d_in[8];
    const float* Wnv2   = (const float*)d_in[9];
    const float* pe_w1  = (const float*)d_in[10];
    const float* pe_b1  = (const float*)d_in[11];
    const float* pe_w2  = (const float*)d_in[12];
    // pe_b2 (d_in[13]): constant logit shift per (g,n) -> cancels in softmax
    const float* npe_w1 = (const float*)d_in[14];
    const float* npe_b1 = (const float*)d_in[15];
    const float* npe_w2 = (const float*)d_in[16];
    const float* npe_b2 = (const float*)d_in[17];
    const int*   idx    = (const int*)d_in[18];
    float* out = (float*)d_out;

    // ws layout (floats): cent[65536] | Qbuf[65536] | nkpe[8192] | nv2j[8192] | tanh[512]
    float* cent  = (float*)d_ws;
    float* Qbuf  = cent + 65536;
    float* nkpeW = Qbuf + 65536;
    float* nv2jW = nkpeW + 8192;
    float* tanhW = nv2jW + 8192;

    hipMemsetAsync(cent, 0, (size_t)65536 * sizeof(float), stream);
    prep_q<<<256, 256, 0, stream>>>(Wq, Wk, pe_w2, Qbuf);
    local_v5<<<4096, 256, 0, stream>>>(x, abs_x, points, Wv, pe_w1, pe_b1,
                                       idx, Qbuf, out, cent);
    topk_prep_kernel<<<32, 256, 0, stream>>>(abs_x, points, Wnk, Wnv2,
                                             npe_w1, npe_b1, npe_w2, npe_b2,
                                             cent, nkpeW, nv2jW, tanhW);
    nonlocal_kernel<<<8 * 32, 256, 0, stream>>>(abs_x, Wnq, Wnv1, Wnv2,
                                                nkpeW, nv2jW, tanhW, out);
}